// Round 1
// baseline (1453.755 us; speedup 1.0000x reference)
//
#include <hip/hip_runtime.h>
#include <math.h>

#define NUM_HEADS 8
#define NUM_GROUPS 32
#define EPS 1e-5f

// Problem constants (from reference setup_inputs)
constexpr int B  = 16;
constexpr int C  = 512;
constexpr int HW = 1024;   // 32*32
constexpr int HD = 64;     // C / NUM_HEADS
constexpr int CPG = C / NUM_GROUPS;  // 16 channels per group
constexpr int GROUP_N = CPG * HW;    // 16384 elements per group

// ---------------------------------------------------------------------------
// Kernel 1: GroupNorm. One block per (b, group). 256 threads.
// ---------------------------------------------------------------------------
__global__ __launch_bounds__(256)
void groupnorm_kernel(const float* __restrict__ x,
                      const float* __restrict__ gamma,
                      const float* __restrict__ beta,
                      float* __restrict__ xn) {
    const int bg = blockIdx.x;
    const int b = bg / NUM_GROUPS, g = bg % NUM_GROUPS;
    const size_t base = ((size_t)b * C + (size_t)g * CPG) * HW;
    const float4* xp4 = (const float4*)(x + base);
    float4* op4 = (float4*)(xn + base);

    float sum = 0.f, sumsq = 0.f;
    const int n4 = GROUP_N / 4;  // 4096
    for (int i = threadIdx.x; i < n4; i += blockDim.x) {
        float4 v = xp4[i];
        sum += v.x + v.y + v.z + v.w;
        sumsq += v.x * v.x + v.y * v.y + v.z * v.z + v.w * v.w;
    }
    // wave reduce (width 64)
    #pragma unroll
    for (int off = 32; off > 0; off >>= 1) {
        sum   += __shfl_down(sum, off, 64);
        sumsq += __shfl_down(sumsq, off, 64);
    }
    __shared__ float s_sum[4], s_sq[4];
    const int wid = threadIdx.x >> 6, lane = threadIdx.x & 63;
    if (lane == 0) { s_sum[wid] = sum; s_sq[wid] = sumsq; }
    __syncthreads();
    const float tsum = s_sum[0] + s_sum[1] + s_sum[2] + s_sum[3];
    const float tsq  = s_sq[0] + s_sq[1] + s_sq[2] + s_sq[3];
    const float mean = tsum * (1.0f / GROUP_N);
    const float var  = tsq * (1.0f / GROUP_N) - mean * mean;
    const float rstd = rsqrtf(var + EPS);

    for (int i = threadIdx.x; i < n4; i += blockDim.x) {
        const int cl = i / (HW / 4);          // channel-local 0..15
        const int cc = g * CPG + cl;
        const float ga = gamma[cc] * rstd;
        const float be = beta[cc] - mean * ga;
        float4 v = xp4[i];
        v.x = v.x * ga + be;
        v.y = v.y * ga + be;
        v.z = v.z * ga + be;
        v.w = v.w * ga + be;
        op4[i] = v;
    }
}

// ---------------------------------------------------------------------------
// Kernel 2: batched GEMM  Cm[z] = A (MxK, shared) @ Bm[z] (KxN) + bias (+resid)
// 64x64 tile, BK=16, 256 threads, 4x4 microtile per thread.
// ---------------------------------------------------------------------------
__global__ __launch_bounds__(256)
void gemm_bias_kernel(const float* __restrict__ A,     // M x K row-major
                      const float* __restrict__ Bm,    // batched K x N
                      const float* __restrict__ bias,  // M
                      const float* __restrict__ resid, // batched M x N or null
                      float* __restrict__ Cm,          // batched M x N
                      int M, int K, int N) {
    constexpr int BM = 64, BN = 64, BK = 16;
    const int batch = blockIdx.z;
    const float* Bp = Bm + (size_t)batch * K * N;
    float* Cp = Cm + (size_t)batch * M * N;
    const float* Rp = resid ? resid + (size_t)batch * M * N : nullptr;

    __shared__ float As[BK][BM + 4];
    __shared__ float Bs[BK][BN + 4];

    const int tid = threadIdx.x;
    const int tx = tid & 15, ty = tid >> 4;
    const int mBase = blockIdx.y * BM, nBase = blockIdx.x * BN;

    float acc[4][4] = {};

    for (int k0 = 0; k0 < K; k0 += BK) {
        // A tile: 64 rows x 16 k, one float4 along K per thread
        {
            const int row = tid >> 2;      // 0..63
            const int qk = tid & 3;        // 0..3
            const float4 av = *(const float4*)(A + (size_t)(mBase + row) * K + k0 + qk * 4);
            As[qk * 4 + 0][row] = av.x;
            As[qk * 4 + 1][row] = av.y;
            As[qk * 4 + 2][row] = av.z;
            As[qk * 4 + 3][row] = av.w;
        }
        // B tile: 16 k-rows x 64 n, one float4 along N per thread
        {
            const int krow = tid >> 4;     // 0..15
            const int qn = tid & 15;       // 0..15
            const float4 bv = *(const float4*)(Bp + (size_t)(k0 + krow) * N + nBase + qn * 4);
            *(float4*)&Bs[krow][qn * 4] = bv;
        }
        __syncthreads();
        #pragma unroll
        for (int k = 0; k < BK; ++k) {
            float a0[4], b0[4];
            *(float4*)a0 = *(const float4*)&As[k][ty * 4];
            *(float4*)b0 = *(const float4*)&Bs[k][tx * 4];
            #pragma unroll
            for (int i = 0; i < 4; ++i)
                #pragma unroll
                for (int j = 0; j < 4; ++j)
                    acc[i][j] += a0[i] * b0[j];
        }
        __syncthreads();
    }

    #pragma unroll
    for (int i = 0; i < 4; ++i) {
        const int m = mBase + ty * 4 + i;
        const float bv = bias[m];
        float4 r;
        r.x = acc[i][0] + bv; r.y = acc[i][1] + bv;
        r.z = acc[i][2] + bv; r.w = acc[i][3] + bv;
        const size_t off = (size_t)m * N + nBase + tx * 4;
        if (Rp) {
            const float4 rv = *(const float4*)(Rp + off);
            r.x += rv.x; r.y += rv.y; r.z += rv.z; r.w += rv.w;
        }
        *(float4*)(Cp + off) = r;
    }
}

// ---------------------------------------------------------------------------
// Kernel 3: flash attention. One block per (b, head, 64-query tile).
// qkv layout: [b][1536][1024] with q = rows 0..511, k = 512..1023, v = 1024..1535,
// head h occupies 64 consecutive rows (d-major, t contiguous).
// ---------------------------------------------------------------------------
__global__ __launch_bounds__(256)
void attn_kernel(const float* __restrict__ qkv, float* __restrict__ out) {
    const int qt = blockIdx.x & 15;         // query tile 0..15
    const int bh = blockIdx.x >> 4;
    const int h = bh & (NUM_HEADS - 1), b = bh / NUM_HEADS;

    const size_t bhOff = ((size_t)b * (3 * C) + (size_t)h * HD) * HW;
    const float* qp = qkv + bhOff;
    const float* kp = qkv + bhOff + (size_t)C * HW;
    const float* vp = qkv + bhOff + (size_t)(2 * C) * HW;

    __shared__ float Ks[64][68];  // [j][d]
    __shared__ float Vs[64][68];  // [j][d]
    __shared__ float Ss[64][68];  // [qi][j]

    const int tid = threadIdx.x;
    const int qi = tid & 63;      // query row within tile / load column
    const int grp = tid >> 6;     // 0..3

    // Q row for this thread, straight from global (coalesced: qi varies over lanes)
    float qreg[HD];
    #pragma unroll
    for (int d = 0; d < HD; ++d)
        qreg[d] = qp[(size_t)d * HW + qt * 64 + qi];

    float m = -INFINITY, l = 0.f;
    float acc[16];
    #pragma unroll
    for (int i = 0; i < 16; ++i) acc[i] = 0.f;

    const float scale = 0.125f;  // 1/sqrt(64)
    const int dBase = grp * 16;

    for (int s0 = 0; s0 < HW; s0 += 64) {
        __syncthreads();  // previous iteration done reading Ks/Vs/Ss
        // stage K, V chunk: Ks[j][d] = k[d][s0+j]
        #pragma unroll
        for (int r = 0; r < 16; ++r) {
            const int d = r * 4 + grp;
            Ks[qi][d] = kp[(size_t)d * HW + s0 + qi];
            Vs[qi][d] = vp[(size_t)d * HW + s0 + qi];
        }
        __syncthreads();
        // S chunk: this thread does row qi, keys j = grp*16 .. +16
        #pragma unroll 1
        for (int jj = 0; jj < 16; ++jj) {
            const int j = grp * 16 + jj;
            float s = 0.f;
            #pragma unroll
            for (int d = 0; d < HD; ++d)
                s += qreg[d] * Ks[j][d];
            Ss[qi][j] = s * scale;
        }
        __syncthreads();
        // online softmax + PV for row qi, dims dBase..dBase+15
        float mc = -INFINITY;
        #pragma unroll
        for (int j = 0; j < 64; ++j) mc = fmaxf(mc, Ss[qi][j]);
        const float mNew = fmaxf(m, mc);
        const float alpha = __expf(m - mNew);
        l *= alpha;
        #pragma unroll
        for (int i = 0; i < 16; ++i) acc[i] *= alpha;
        #pragma unroll 1
        for (int j = 0; j < 64; ++j) {
            const float p = __expf(Ss[qi][j] - mNew);
            l += p;
            #pragma unroll
            for (int i = 0; i < 16; ++i)
                acc[i] += p * Vs[j][dBase + i];
        }
        m = mNew;
    }

    // write out[b][h*64 + d][t]
    const float inv = 1.f / l;
    float* op = out + ((size_t)b * C + (size_t)h * HD) * HW;
    #pragma unroll
    for (int i = 0; i < 16; ++i)
        op[(size_t)(dBase + i) * HW + qt * 64 + qi] = acc[i] * inv;
}

// ---------------------------------------------------------------------------
// Launch
// ---------------------------------------------------------------------------
extern "C" void kernel_launch(void* const* d_in, const int* in_sizes, int n_in,
                              void* d_out, int out_size, void* d_ws, size_t ws_size,
                              hipStream_t stream) {
    const float* x        = (const float*)d_in[0];
    const float* gn_gamma = (const float*)d_in[1];
    const float* gn_beta  = (const float*)d_in[2];
    const float* qkv_w    = (const float*)d_in[3];
    const float* qkv_b    = (const float*)d_in[4];
    const float* proj_w   = (const float*)d_in[5];
    const float* proj_b   = (const float*)d_in[6];
    float* out = (float*)d_out;

    // workspace layout
    float* xn  = (float*)d_ws;                                  // 16*512*1024 f32 = 32 MiB
    float* qkv = (float*)((char*)d_ws + (size_t)B * C * HW * 4); // 16*1536*1024 f32 = 96 MiB
    float* attn_out = xn;  // xn dead after QKV GEMM; reuse

    // 1. GroupNorm
    groupnorm_kernel<<<B * NUM_GROUPS, 256, 0, stream>>>(x, gn_gamma, gn_beta, xn);

    // 2. QKV projection: per batch (1536x512) @ (512x1024) + bias
    {
        dim3 grid(HW / 64, (3 * C) / 64, B);
        gemm_bias_kernel<<<grid, 256, 0, stream>>>(qkv_w, xn, qkv_b, nullptr, qkv,
                                                   3 * C, C, HW);
    }

    // 3. Attention
    attn_kernel<<<B * NUM_HEADS * (HW / 64), 256, 0, stream>>>(qkv, attn_out);

    // 4. Proj + bias + residual
    {
        dim3 grid(HW / 64, C / 64, B);
        gemm_bias_kernel<<<grid, 256, 0, stream>>>(proj_w, attn_out, proj_b, x, out,
                                                   C, C, HW);
    }
}

// Round 2
// 640.447 us; speedup vs baseline: 2.2699x; 2.2699x over previous
//
#include <hip/hip_runtime.h>
#include <math.h>

#define NUM_HEADS 8
#define NUM_GROUPS 32
#define EPS 1e-5f

constexpr int B  = 16;
constexpr int C  = 512;
constexpr int HW = 1024;   // 32*32
constexpr int HD = 64;
constexpr int CPG = C / NUM_GROUPS;   // 16
constexpr int GROUP_N = CPG * HW;     // 16384

typedef short bf16x8 __attribute__((ext_vector_type(8)));
typedef float f32x4  __attribute__((ext_vector_type(4)));

__device__ inline unsigned short f2bf(float f) {
    union { float f; unsigned int u; } v; v.f = f;
    unsigned int r = (v.u + 0x7FFFu + ((v.u >> 16) & 1u)) >> 16;
    return (unsigned short)r;
}

// ---------------------------------------------------------------------------
// Kernel 1: GroupNorm (fp32), unchanged from round 1.
// ---------------------------------------------------------------------------
__global__ __launch_bounds__(256)
void groupnorm_kernel(const float* __restrict__ x,
                      const float* __restrict__ gamma,
                      const float* __restrict__ beta,
                      float* __restrict__ xn) {
    const int bg = blockIdx.x;
    const int b = bg / NUM_GROUPS, g = bg % NUM_GROUPS;
    const size_t base = ((size_t)b * C + (size_t)g * CPG) * HW;
    const float4* xp4 = (const float4*)(x + base);
    float4* op4 = (float4*)(xn + base);

    float sum = 0.f, sumsq = 0.f;
    const int n4 = GROUP_N / 4;
    for (int i = threadIdx.x; i < n4; i += blockDim.x) {
        float4 v = xp4[i];
        sum += v.x + v.y + v.z + v.w;
        sumsq += v.x * v.x + v.y * v.y + v.z * v.z + v.w * v.w;
    }
    #pragma unroll
    for (int off = 32; off > 0; off >>= 1) {
        sum   += __shfl_down(sum, off, 64);
        sumsq += __shfl_down(sumsq, off, 64);
    }
    __shared__ float s_sum[4], s_sq[4];
    const int wid = threadIdx.x >> 6, lane = threadIdx.x & 63;
    if (lane == 0) { s_sum[wid] = sum; s_sq[wid] = sumsq; }
    __syncthreads();
    const float tsum = s_sum[0] + s_sum[1] + s_sum[2] + s_sum[3];
    const float tsq  = s_sq[0] + s_sq[1] + s_sq[2] + s_sq[3];
    const float mean = tsum * (1.0f / GROUP_N);
    const float var  = tsq * (1.0f / GROUP_N) - mean * mean;
    const float rstd = rsqrtf(var + EPS);

    for (int i = threadIdx.x; i < n4; i += blockDim.x) {
        const int cl = i / (HW / 4);
        const int cc = g * CPG + cl;
        const float ga = gamma[cc] * rstd;
        const float be = beta[cc] - mean * ga;
        float4 v = xp4[i];
        v.x = v.x * ga + be;
        v.y = v.y * ga + be;
        v.z = v.z * ga + be;
        v.w = v.w * ga + be;
        op4[i] = v;
    }
}

// ---------------------------------------------------------------------------
// Kernel 2a: fp32 GEMM, bf16 output (QKV projection).
// C[z] = A (MxK) @ B[z] (KxN) + bias, stored as bf16.
// ---------------------------------------------------------------------------
__global__ __launch_bounds__(256)
void gemm_bias_bf16out_kernel(const float* __restrict__ A,
                              const float* __restrict__ Bm,
                              const float* __restrict__ bias,
                              unsigned short* __restrict__ Cm,
                              int M, int K, int N) {
    constexpr int BM = 64, BN = 64, BK = 16;
    const int batch = blockIdx.z;
    const float* Bp = Bm + (size_t)batch * K * N;
    unsigned short* Cp = Cm + (size_t)batch * M * N;

    __shared__ float As[BK][BM + 4];
    __shared__ float Bs[BK][BN + 4];

    const int tid = threadIdx.x;
    const int tx = tid & 15, ty = tid >> 4;
    const int mBase = blockIdx.y * BM, nBase = blockIdx.x * BN;

    float acc[4][4] = {};

    for (int k0 = 0; k0 < K; k0 += BK) {
        {
            const int row = tid >> 2;
            const int qk = tid & 3;
            const float4 av = *(const float4*)(A + (size_t)(mBase + row) * K + k0 + qk * 4);
            As[qk * 4 + 0][row] = av.x;
            As[qk * 4 + 1][row] = av.y;
            As[qk * 4 + 2][row] = av.z;
            As[qk * 4 + 3][row] = av.w;
        }
        {
            const int krow = tid >> 4;
            const int qn = tid & 15;
            const float4 bv = *(const float4*)(Bp + (size_t)(k0 + krow) * N + nBase + qn * 4);
            *(float4*)&Bs[krow][qn * 4] = bv;
        }
        __syncthreads();
        #pragma unroll
        for (int k = 0; k < BK; ++k) {
            float a0[4], b0[4];
            *(float4*)a0 = *(const float4*)&As[k][ty * 4];
            *(float4*)b0 = *(const float4*)&Bs[k][tx * 4];
            #pragma unroll
            for (int i = 0; i < 4; ++i)
                #pragma unroll
                for (int j = 0; j < 4; ++j)
                    acc[i][j] += a0[i] * b0[j];
        }
        __syncthreads();
    }

    #pragma unroll
    for (int i = 0; i < 4; ++i) {
        const int m = mBase + ty * 4 + i;
        const float bv = bias[m];
        ushort4 r;
        r.x = f2bf(acc[i][0] + bv);
        r.y = f2bf(acc[i][1] + bv);
        r.z = f2bf(acc[i][2] + bv);
        r.w = f2bf(acc[i][3] + bv);
        *(ushort4*)(Cp + (size_t)m * N + nBase + tx * 4) = r;
    }
}

// ---------------------------------------------------------------------------
// Kernel 2b: fp32 GEMM, fp32 out + residual (proj), unchanged from round 1.
// ---------------------------------------------------------------------------
__global__ __launch_bounds__(256)
void gemm_bias_kernel(const float* __restrict__ A,
                      const float* __restrict__ Bm,
                      const float* __restrict__ bias,
                      const float* __restrict__ resid,
                      float* __restrict__ Cm,
                      int M, int K, int N) {
    constexpr int BM = 64, BN = 64, BK = 16;
    const int batch = blockIdx.z;
    const float* Bp = Bm + (size_t)batch * K * N;
    float* Cp = Cm + (size_t)batch * M * N;
    const float* Rp = resid ? resid + (size_t)batch * M * N : nullptr;

    __shared__ float As[BK][BM + 4];
    __shared__ float Bs[BK][BN + 4];

    const int tid = threadIdx.x;
    const int tx = tid & 15, ty = tid >> 4;
    const int mBase = blockIdx.y * BM, nBase = blockIdx.x * BN;

    float acc[4][4] = {};

    for (int k0 = 0; k0 < K; k0 += BK) {
        {
            const int row = tid >> 2;
            const int qk = tid & 3;
            const float4 av = *(const float4*)(A + (size_t)(mBase + row) * K + k0 + qk * 4);
            As[qk * 4 + 0][row] = av.x;
            As[qk * 4 + 1][row] = av.y;
            As[qk * 4 + 2][row] = av.z;
            As[qk * 4 + 3][row] = av.w;
        }
        {
            const int krow = tid >> 4;
            const int qn = tid & 15;
            const float4 bv = *(const float4*)(Bp + (size_t)(k0 + krow) * N + nBase + qn * 4);
            *(float4*)&Bs[krow][qn * 4] = bv;
        }
        __syncthreads();
        #pragma unroll
        for (int k = 0; k < BK; ++k) {
            float a0[4], b0[4];
            *(float4*)a0 = *(const float4*)&As[k][ty * 4];
            *(float4*)b0 = *(const float4*)&Bs[k][tx * 4];
            #pragma unroll
            for (int i = 0; i < 4; ++i)
                #pragma unroll
                for (int j = 0; j < 4; ++j)
                    acc[i][j] += a0[i] * b0[j];
        }
        __syncthreads();
    }

    #pragma unroll
    for (int i = 0; i < 4; ++i) {
        const int m = mBase + ty * 4 + i;
        const float bv = bias[m];
        float4 r;
        r.x = acc[i][0] + bv; r.y = acc[i][1] + bv;
        r.z = acc[i][2] + bv; r.w = acc[i][3] + bv;
        const size_t off = (size_t)m * N + nBase + tx * 4;
        if (Rp) {
            const float4 rv = *(const float4*)(Rp + off);
            r.x += rv.x; r.y += rv.y; r.z += rv.z; r.w += rv.w;
        }
        *(float4*)(Cp + off) = r;
    }
}

// ---------------------------------------------------------------------------
// Kernel 3: transpose Q,K from qkv bf16 [b][1536][1024] into
//   Qt/Kt [bh][t=1024][d=64] bf16 (d-contiguous). Q scaled by 0.125 (exact).
// ---------------------------------------------------------------------------
__global__ __launch_bounds__(256)
void transpose_qk_kernel(const unsigned short* __restrict__ qkvb,
                         unsigned short* __restrict__ Qt,
                         unsigned short* __restrict__ Kt) {
    const int bh = blockIdx.x, b = bh >> 3, h = bh & 7;
    const int t0 = blockIdx.y * 64;
    const int which = blockIdx.z;  // 0 = Q, 1 = K

    __shared__ unsigned short Ts[64 * 66];  // stride 66: odd dword stride

    const unsigned short* src = qkvb + ((size_t)b * 1536 + (size_t)which * 512 + h * 64) * 1024;
    unsigned short* dst = (which ? Kt : Qt) + ((size_t)bh * 1024 + t0) * 64;

    const int t8 = threadIdx.x & 7;
    const int d0 = threadIdx.x >> 3;
    #pragma unroll
    for (int p = 0; p < 2; ++p) {
        const int d = d0 + 32 * p;
        const uint4 v = *(const uint4*)(src + (size_t)d * 1024 + t0 + t8 * 8);
        unsigned int* tw = (unsigned int*)&Ts[d * 66 + t8 * 8];
        tw[0] = v.x; tw[1] = v.y; tw[2] = v.z; tw[3] = v.w;
    }
    __syncthreads();
    const int d8 = threadIdx.x & 7;
    const int tl0 = threadIdx.x >> 3;
    #pragma unroll
    for (int p = 0; p < 2; ++p) {
        const int t = tl0 + 32 * p;
        unsigned short tmp[8];
        #pragma unroll
        for (int i = 0; i < 8; ++i) {
            unsigned short u = Ts[(8 * d8 + i) * 66 + t];
            if (which == 0) {
                union { float f; unsigned int ui; } vv;
                vv.ui = ((unsigned int)u) << 16;
                vv.f *= 0.125f;                  // exact pow2 scale
                u = (unsigned short)(vv.ui >> 16);
            }
            tmp[i] = u;
        }
        *(uint4*)(dst + (size_t)t * 64 + 8 * d8) = *(const uint4*)tmp;
    }
}

// ---------------------------------------------------------------------------
// Kernel 4: MFMA flash attention.
// Block = (bh, qtile of 64). 4 waves; wave w owns output t-columns [16w,16w+16).
// S^T = K^T Q (m=s, n=t, k=d), softmax over s in-register (shfl over quads),
// P round-trips LDS per-wave, O^T = V P^T (m=d, n=t, k=s).
// ---------------------------------------------------------------------------
__global__ __launch_bounds__(256)
void attn_mfma_kernel(const unsigned short* __restrict__ Qt,
                      const unsigned short* __restrict__ Kt,
                      const unsigned short* __restrict__ qkvb,
                      float* __restrict__ out) {
    const int bh = blockIdx.x;
    const int b = bh >> 3, h = bh & 7;
    const int t0 = blockIdx.y * 64;
    const int tid = threadIdx.x;
    const int w = tid >> 6, lane = tid & 63;
    const int lo = lane & 15, q4 = lane >> 4;

    __shared__ __align__(16) unsigned short Ks[64][72];      // [s][d] pad->stride 144B
    __shared__ __align__(16) unsigned short Vs[64][72];      // [d][s]
    __shared__ __align__(16) unsigned short Ps[4][16][72];   // per-wave [t][s]

    const unsigned short* Qp = Qt + ((size_t)bh * 1024 + t0) * 64;
    const unsigned short* Kp = Kt + (size_t)bh * 1024 * 64;
    const unsigned short* Vp = qkvb + ((size_t)b * 1536 + 1024 + (size_t)h * 64) * 1024;

    // persistent Q B-fragments (n=t=lo, k=d=32*kh+8*q4+j), Q pre-scaled by 1/8
    bf16x8 qf0, qf1;
    {
        const int t = 16 * w + lo;
        qf0 = *(const bf16x8*)(Qp + (size_t)t * 64 + 8 * q4);
        qf1 = *(const bf16x8*)(Qp + (size_t)t * 64 + 32 + 8 * q4);
    }

    f32x4 oacc[4] = {{0.f,0.f,0.f,0.f},{0.f,0.f,0.f,0.f},{0.f,0.f,0.f,0.f},{0.f,0.f,0.f,0.f}};
    float mrun = -INFINITY, lrun = 0.f;

    for (int s0 = 0; s0 < HW; s0 += 64) {
        __syncthreads();
        // ---- stage K chunk (8 KB contiguous in Kt) and V chunk ----
        {
            const uint4* ksrc = (const uint4*)(Kp + (size_t)s0 * 64);
            int c = tid;
            uint4 kv = ksrc[c];
            *(uint4*)&Ks[c >> 3][(c & 7) * 8] = kv;
            c += 256;
            kv = ksrc[c];
            *(uint4*)&Ks[c >> 3][(c & 7) * 8] = kv;

            c = tid;
            uint4 vv = *(const uint4*)(Vp + (size_t)(c >> 3) * 1024 + s0 + (c & 7) * 8);
            *(uint4*)&Vs[c >> 3][(c & 7) * 8] = vv;
            c += 256;
            vv = *(const uint4*)(Vp + (size_t)(c >> 3) * 1024 + s0 + (c & 7) * 8);
            *(uint4*)&Vs[c >> 3][(c & 7) * 8] = vv;
        }
        __syncthreads();

        // ---- S^T = K^T Q ----
        f32x4 sacc[4] = {{0.f,0.f,0.f,0.f},{0.f,0.f,0.f,0.f},{0.f,0.f,0.f,0.f},{0.f,0.f,0.f,0.f}};
        #pragma unroll
        for (int mt = 0; mt < 4; ++mt) {
            const bf16x8 a0 = *(const bf16x8*)&Ks[16 * mt + lo][8 * q4];
            const bf16x8 a1 = *(const bf16x8*)&Ks[16 * mt + lo][32 + 8 * q4];
            sacc[mt] = __builtin_amdgcn_mfma_f32_16x16x32_bf16(a0, qf0, sacc[mt], 0, 0, 0);
            sacc[mt] = __builtin_amdgcn_mfma_f32_16x16x32_bf16(a1, qf1, sacc[mt], 0, 0, 0);
        }

        // ---- online softmax over s for column t = lo ----
        float cm = -INFINITY;
        #pragma unroll
        for (int mt = 0; mt < 4; ++mt) {
            cm = fmaxf(cm, fmaxf(fmaxf(sacc[mt][0], sacc[mt][1]),
                                 fmaxf(sacc[mt][2], sacc[mt][3])));
        }
        cm = fmaxf(cm, __shfl_xor(cm, 16, 64));
        cm = fmaxf(cm, __shfl_xor(cm, 32, 64));
        const float mNew = fmaxf(mrun, cm);

        float psum = 0.f;
        #pragma unroll
        for (int mt = 0; mt < 4; ++mt) {
            const float p0 = __expf(sacc[mt][0] - mNew);
            const float p1 = __expf(sacc[mt][1] - mNew);
            const float p2 = __expf(sacc[mt][2] - mNew);
            const float p3 = __expf(sacc[mt][3] - mNew);
            psum += (p0 + p1) + (p2 + p3);
            ushort4 pk;
            pk.x = f2bf(p0); pk.y = f2bf(p1); pk.z = f2bf(p2); pk.w = f2bf(p3);
            // P[t][s]: s = 16*mt + 4*q4 + r, t = lo
            *(ushort4*)&Ps[w][lo][16 * mt + 4 * q4] = pk;
        }
        psum += __shfl_xor(psum, 16, 64);
        psum += __shfl_xor(psum, 32, 64);

        const float alpha = __expf(mrun - mNew);
        lrun = lrun * alpha + psum;
        mrun = mNew;
        #pragma unroll
        for (int mt = 0; mt < 4; ++mt) {
            oacc[mt][0] *= alpha; oacc[mt][1] *= alpha;
            oacc[mt][2] *= alpha; oacc[mt][3] *= alpha;
        }

        // ---- O^T += V P^T (wave-private Ps; same-wave LDS RAW, no barrier) ----
        const bf16x8 bp0 = *(const bf16x8*)&Ps[w][lo][8 * q4];
        const bf16x8 bp1 = *(const bf16x8*)&Ps[w][lo][32 + 8 * q4];
        #pragma unroll
        for (int mt = 0; mt < 4; ++mt) {
            const bf16x8 av0 = *(const bf16x8*)&Vs[16 * mt + lo][8 * q4];
            const bf16x8 av1 = *(const bf16x8*)&Vs[16 * mt + lo][32 + 8 * q4];
            oacc[mt] = __builtin_amdgcn_mfma_f32_16x16x32_bf16(av0, bp0, oacc[mt], 0, 0, 0);
            oacc[mt] = __builtin_amdgcn_mfma_f32_16x16x32_bf16(av1, bp1, oacc[mt], 0, 0, 0);
        }
    }

    // ---- epilogue: O^T[d][t] -> out[b][h*64+d][t0+16w+lo] ----
    const float inv = 1.0f / lrun;
    float* op = out + ((size_t)b * C + (size_t)h * HD) * HW + t0 + 16 * w + lo;
    #pragma unroll
    for (int mt = 0; mt < 4; ++mt) {
        #pragma unroll
        for (int r = 0; r < 4; ++r) {
            op[(size_t)(16 * mt + 4 * q4 + r) * HW] = oacc[mt][r] * inv;
        }
    }
}

// ---------------------------------------------------------------------------
// Launch
// ---------------------------------------------------------------------------
extern "C" void kernel_launch(void* const* d_in, const int* in_sizes, int n_in,
                              void* d_out, int out_size, void* d_ws, size_t ws_size,
                              hipStream_t stream) {
    const float* x        = (const float*)d_in[0];
    const float* gn_gamma = (const float*)d_in[1];
    const float* gn_beta  = (const float*)d_in[2];
    const float* qkv_w    = (const float*)d_in[3];
    const float* qkv_b    = (const float*)d_in[4];
    const float* proj_w   = (const float*)d_in[5];
    const float* proj_b   = (const float*)d_in[6];
    float* out = (float*)d_out;

    // workspace layout (112 MiB total)
    char* wsc = (char*)d_ws;
    float* xn = (float*)wsc;                                   // 32 MiB (reused as attn_out)
    unsigned short* qkvb = (unsigned short*)(wsc + 33554432);  // 48 MiB bf16 [b][1536][1024]
    unsigned short* Qt   = (unsigned short*)(wsc + 83886080);  // 16 MiB bf16 [bh][1024][64]
    unsigned short* Kt   = (unsigned short*)(wsc + 100663296); // 16 MiB bf16 [bh][1024][64]
    float* attn_out = xn;

    // 1. GroupNorm
    groupnorm_kernel<<<B * NUM_GROUPS, 256, 0, stream>>>(x, gn_gamma, gn_beta, xn);

    // 2. QKV projection (fp32 compute, bf16 out)
    {
        dim3 grid(HW / 64, (3 * C) / 64, B);
        gemm_bias_bf16out_kernel<<<grid, 256, 0, stream>>>(qkv_w, xn, qkv_b, qkvb,
                                                           3 * C, C, HW);
    }

    // 3. Transpose Q,K to [t][d] bf16 (Q pre-scaled by 0.125)
    {
        dim3 grid(B * NUM_HEADS, HW / 64, 2);
        transpose_qk_kernel<<<grid, 256, 0, stream>>>(qkvb, Qt, Kt);
    }

    // 4. MFMA flash attention
    {
        dim3 grid(B * NUM_HEADS, HW / 64);
        attn_mfma_kernel<<<grid, 256, 0, stream>>>(Qt, Kt, qkvb, attn_out);
    }

    // 5. Proj + bias + residual (fp32)
    {
        dim3 grid(HW / 64, C / 64, B);
        gemm_bias_kernel<<<grid, 256, 0, stream>>>(proj_w, attn_out, proj_b, x, out,
                                                   C, C, HW);
    }
}

// Round 4
// 265.049 us; speedup vs baseline: 5.4849x; 2.4163x over previous
//
#include <hip/hip_runtime.h>
#include <math.h>

#define NUM_HEADS 8
#define NUM_GROUPS 32
#define EPS 1e-5f

constexpr int B  = 16;
constexpr int C  = 512;
constexpr int HW = 1024;   // 32*32
constexpr int HD = 64;

typedef short bf16x8 __attribute__((ext_vector_type(8)));
typedef float f32x4  __attribute__((ext_vector_type(4)));

#define QSCALE 0.1803368801111f  /* 0.125 * log2(e): softmax done in exp2 space */

__device__ inline unsigned short f2bf(float f) {
    union { float f; unsigned int u; } v; v.f = f;
    unsigned int r = (v.u + 0x7FFFu + ((v.u >> 16) & 1u)) >> 16;
    return (unsigned short)r;
}

// async global->LDS, 16B per lane. LDS dest = wave-uniform base + lane*16.
__device__ __forceinline__ void gld_lds16(void* lds, const void* g) {
    __builtin_amdgcn_global_load_lds(
        (const __attribute__((address_space(1))) void*)g,
        (__attribute__((address_space(3))) void*)lds, 16, 0, 0);
}

// ---------------------------------------------------------------------------
// Kernel 1: GroupNorm -> xnT bf16 [b][t=1024][c=512] (c-contiguous).
// One block per (b, group). Pass 1: stats. Pass 2: transpose-write.
// ---------------------------------------------------------------------------
__global__ __launch_bounds__(256)
void groupnorm_t_kernel(const float* __restrict__ x,
                        const float* __restrict__ gamma,
                        const float* __restrict__ beta,
                        unsigned short* __restrict__ xnT) {
    const int bg = blockIdx.x;
    const int b = bg >> 5, g = bg & 31;
    const size_t base = ((size_t)b * C + (size_t)g * 16) * HW;
    const float4* xp4 = (const float4*)(x + base);

    float sum = 0.f, sumsq = 0.f;
    for (int i = threadIdx.x; i < 4096; i += 256) {
        float4 v = xp4[i];
        sum += v.x + v.y + v.z + v.w;
        sumsq += v.x * v.x + v.y * v.y + v.z * v.z + v.w * v.w;
    }
    #pragma unroll
    for (int off = 32; off > 0; off >>= 1) {
        sum   += __shfl_down(sum, off, 64);
        sumsq += __shfl_down(sumsq, off, 64);
    }
    __shared__ float s_sum[4], s_sq[4];
    const int wid = threadIdx.x >> 6, lane = threadIdx.x & 63;
    if (lane == 0) { s_sum[wid] = sum; s_sq[wid] = sumsq; }
    __syncthreads();
    const float tsum = s_sum[0] + s_sum[1] + s_sum[2] + s_sum[3];
    const float tsq  = s_sq[0] + s_sq[1] + s_sq[2] + s_sq[3];
    const float mean = tsum * (1.0f / 16384.f);
    const float var  = tsq * (1.0f / 16384.f) - mean * mean;
    const float rstd = rsqrtf(var + EPS);

    float ga[16], be[16];
    #pragma unroll
    for (int cl = 0; cl < 16; ++cl) {
        ga[cl] = gamma[g * 16 + cl] * rstd;
        be[cl] = beta[g * 16 + cl] - mean * ga[cl];
    }

    #pragma unroll
    for (int p = 0; p < 4; ++p) {
        const int t = threadIdx.x + p * 256;
        unsigned short pk[16];
        #pragma unroll
        for (int cl = 0; cl < 16; ++cl) {
            const float v = x[base + (size_t)cl * HW + t];
            pk[cl] = f2bf(v * ga[cl] + be[cl]);
        }
        unsigned short* dst = xnT + ((size_t)(b * 1024 + t)) * 512 + g * 16;
        *(uint4*)dst = *(const uint4*)pk;
        *(uint4*)(dst + 8) = *(const uint4*)(pk + 8);
    }
}

// ---------------------------------------------------------------------------
// Kernel 2: weight conversion fp32 -> bf16. wqb (1536x512) then wpb (512x512)
// contiguous at wqb + 786432.
// ---------------------------------------------------------------------------
__global__ __launch_bounds__(256)
void wconv_kernel(const float* __restrict__ qkv_w,
                  const float* __restrict__ proj_w,
                  unsigned short* __restrict__ wqb) {
    const int i = blockIdx.x * 256 + threadIdx.x;   // float4 index
    const int n1 = 786432 / 4;
    const int nt = 1048576 / 4;
    if (i >= nt) return;
    const float4 v = (i < n1) ? ((const float4*)qkv_w)[i]
                              : ((const float4*)proj_w)[i - n1];
    ushort4 r;
    r.x = f2bf(v.x); r.y = f2bf(v.y); r.z = f2bf(v.z); r.w = f2bf(v.w);
    ((ushort4*)wqb)[i] = r;
}

// ---------------------------------------------------------------------------
// Shared MFMA GEMM core: C(128x128) = A(128xK) * B'(128xK)^T, K=512, BK=32.
// A rows k-contiguous (stride 1024B), B' rows k-contiguous (stride 1024B).
// global_load_lds staging, XOR-swizzled 16B k-chunks (conflict-free ds_read).
// 4 waves: wave (wm,wn) owns 64x64; acc[4][4] of 16x16 frags.
// ---------------------------------------------------------------------------
__device__ __forceinline__ void mfma_gemm_core(const char* __restrict__ Ab,
                                               const char* __restrict__ Bb,
                                               unsigned short* As,
                                               unsigned short* Bs,
                                               f32x4 acc[4][4]) {
    const int tid = threadIdx.x;
    const int w = tid >> 6, lane = tid & 63;
    const int lo = lane & 15, q4 = lane >> 4;
    const int wm = w >> 1, wn = w & 1;
    const int lrow = lane >> 2, lkc = lane & 3;

    for (int k0 = 0; k0 < 512; k0 += 32) {
        __syncthreads();
        #pragma unroll
        for (int i = 0; i < 2; ++i) {
            const int row = w * 32 + i * 16 + lrow;
            const int kc = lkc ^ ((row >> 1) & 3);   // swizzle k-chunk
            const size_t goff = (size_t)row * 1024 + k0 * 2 + kc * 16;
            gld_lds16((char*)As + w * 2048 + i * 1024, Ab + goff);
            gld_lds16((char*)Bs + w * 2048 + i * 1024, Bb + goff);
        }
        __syncthreads();

        bf16x8 af[4], bfr[4];
        #pragma unroll
        for (int i = 0; i < 4; ++i) {
            const int ra = wm * 64 + i * 16 + lo;
            af[i]  = *(const bf16x8*)(As + ra * 32 + (q4 ^ ((ra >> 1) & 3)) * 8);
            const int rb = wn * 64 + i * 16 + lo;
            bfr[i] = *(const bf16x8*)(Bs + rb * 32 + (q4 ^ ((rb >> 1) & 3)) * 8);
        }
        #pragma unroll
        for (int mi = 0; mi < 4; ++mi)
            #pragma unroll
            for (int ni = 0; ni < 4; ++ni)
                acc[mi][ni] = __builtin_amdgcn_mfma_f32_16x16x32_bf16(
                    af[mi], bfr[ni], acc[mi][ni], 0, 0, 0);
    }
}

// ---------------------------------------------------------------------------
// Kernel 3: QKV projection GEMM. Epilogue routes per-wave 64-row (=one head)
// chunk: Q -> Qt[bh][t][d] (scaled by QSCALE), K -> Kt[bh][t][d], V -> Vb[b][d][t].
// ---------------------------------------------------------------------------
__global__ __launch_bounds__(256)
void qkv_mfma_kernel(const unsigned short* __restrict__ wqb,
                     const unsigned short* __restrict__ xnT,
                     const float* __restrict__ qkv_b,
                     unsigned short* __restrict__ Qt,
                     unsigned short* __restrict__ Kt,
                     unsigned short* __restrict__ Vb) {
    __shared__ __align__(16) unsigned short As[128 * 32];
    __shared__ __align__(16) unsigned short Bs[128 * 32];
    const int batch = blockIdx.z;
    const int mBase = blockIdx.y * 128, nBase = blockIdx.x * 128;

    f32x4 acc[4][4] = {};
    mfma_gemm_core((const char*)(wqb + (size_t)mBase * 512),
                   (const char*)(xnT + ((size_t)batch * 1024 + nBase) * 512),
                   As, Bs, acc);

    const int tid = threadIdx.x;
    const int w = tid >> 6, lane = tid & 63;
    const int lo = lane & 15, q4 = lane >> 4;
    const int wm = w >> 1, wn = w & 1;
    const int mw = mBase + wm * 64;          // head-aligned 64-row chunk
    const int tb = nBase + wn * 64;

    if (mw < 1024) {
        const bool isQ = mw < 512;
        const int head = (mw >> 6) & 7;
        unsigned short* dst = (isQ ? Qt : Kt) + (((size_t)batch * 8 + head) << 16);
        const float sc = isQ ? QSCALE : 1.0f;
        #pragma unroll
        for (int mi = 0; mi < 4; ++mi) {
            const float4 bq = *(const float4*)(qkv_b + mw + mi * 16 + q4 * 4);
            #pragma unroll
            for (int ni = 0; ni < 4; ++ni) {
                const int t = tb + ni * 16 + lo;
                ushort4 pk;
                pk.x = f2bf((acc[mi][ni][0] + bq.x) * sc);
                pk.y = f2bf((acc[mi][ni][1] + bq.y) * sc);
                pk.z = f2bf((acc[mi][ni][2] + bq.z) * sc);
                pk.w = f2bf((acc[mi][ni][3] + bq.w) * sc);
                *(ushort4*)(dst + (size_t)t * 64 + mi * 16 + q4 * 4) = pk;
            }
        }
    } else {
        unsigned short* dst = Vb + (size_t)batch * 524288 + (size_t)(mw - 1024) * 1024;
        #pragma unroll
        for (int mi = 0; mi < 4; ++mi) {
            const float4 bq = *(const float4*)(qkv_b + mw + mi * 16 + q4 * 4);
            #pragma unroll
            for (int ni = 0; ni < 4; ++ni) {
                const int t = tb + ni * 16 + lo;
                dst[(size_t)(mi * 16 + q4 * 4 + 0) * 1024 + t] = f2bf(acc[mi][ni][0] + bq.x);
                dst[(size_t)(mi * 16 + q4 * 4 + 1) * 1024 + t] = f2bf(acc[mi][ni][1] + bq.y);
                dst[(size_t)(mi * 16 + q4 * 4 + 2) * 1024 + t] = f2bf(acc[mi][ni][2] + bq.z);
                dst[(size_t)(mi * 16 + q4 * 4 + 3) * 1024 + t] = f2bf(acc[mi][ni][3] + bq.w);
            }
        }
    }
}

// ---------------------------------------------------------------------------
// Kernel 4: MFMA flash attention (exp2 softmax; Q pre-scaled by 0.125*log2e).
// Output: attnT bf16 [b][t][c] (c-contiguous, ready as proj B-operand).
// ---------------------------------------------------------------------------
__global__ __launch_bounds__(256)
void attn_mfma_kernel(const unsigned short* __restrict__ Qt,
                      const unsigned short* __restrict__ Kt,
                      const unsigned short* __restrict__ Vb,
                      unsigned short* __restrict__ attnT) {
    const int bh = blockIdx.x;
    const int b = bh >> 3, h = bh & 7;
    const int t0 = blockIdx.y * 64;
    const int tid = threadIdx.x;
    const int w = tid >> 6, lane = tid & 63;
    const int lo = lane & 15, q4 = lane >> 4;

    __shared__ __align__(16) unsigned short Ks[64][72];
    __shared__ __align__(16) unsigned short Vs[64][72];
    __shared__ __align__(16) unsigned short Ps[4][16][72];

    const unsigned short* Qp = Qt + ((size_t)bh * 1024 + t0) * 64;
    const unsigned short* Kp = Kt + (size_t)bh * 1024 * 64;
    const unsigned short* Vp = Vb + ((size_t)b * 512 + h * 64) * 1024;

    bf16x8 qf0, qf1;
    {
        const int t = 16 * w + lo;
        qf0 = *(const bf16x8*)(Qp + (size_t)t * 64 + 8 * q4);
        qf1 = *(const bf16x8*)(Qp + (size_t)t * 64 + 32 + 8 * q4);
    }

    f32x4 oacc[4] = {{0.f,0.f,0.f,0.f},{0.f,0.f,0.f,0.f},{0.f,0.f,0.f,0.f},{0.f,0.f,0.f,0.f}};
    float mrun = -INFINITY, lrun = 0.f;

    for (int s0 = 0; s0 < HW; s0 += 64) {
        __syncthreads();
        {
            const uint4* ksrc = (const uint4*)(Kp + (size_t)s0 * 64);
            int c = tid;
            uint4 kv = ksrc[c];
            *(uint4*)&Ks[c >> 3][(c & 7) * 8] = kv;
            c += 256;
            kv = ksrc[c];
            *(uint4*)&Ks[c >> 3][(c & 7) * 8] = kv;

            c = tid;
            uint4 vv = *(const uint4*)(Vp + (size_t)(c >> 3) * 1024 + s0 + (c & 7) * 8);
            *(uint4*)&Vs[c >> 3][(c & 7) * 8] = vv;
            c += 256;
            vv = *(const uint4*)(Vp + (size_t)(c >> 3) * 1024 + s0 + (c & 7) * 8);
            *(uint4*)&Vs[c >> 3][(c & 7) * 8] = vv;
        }
        __syncthreads();

        f32x4 sacc[4] = {{0.f,0.f,0.f,0.f},{0.f,0.f,0.f,0.f},{0.f,0.f,0.f,0.f},{0.f,0.f,0.f,0.f}};
        #pragma unroll
        for (int mt = 0; mt < 4; ++mt) {
            const bf16x8 a0 = *(const bf16x8*)&Ks[16 * mt + lo][8 * q4];
            const bf16x8 a1 = *(const bf16x8*)&Ks[16 * mt + lo][32 + 8 * q4];
            sacc[mt] = __builtin_amdgcn_mfma_f32_16x16x32_bf16(a0, qf0, sacc[mt], 0, 0, 0);
            sacc[mt] = __builtin_amdgcn_mfma_f32_16x16x32_bf16(a1, qf1, sacc[mt], 0, 0, 0);
        }

        float cm = -INFINITY;
        #pragma unroll
        for (int mt = 0; mt < 4; ++mt)
            cm = fmaxf(cm, fmaxf(fmaxf(sacc[mt][0], sacc[mt][1]),
                                 fmaxf(sacc[mt][2], sacc[mt][3])));
        cm = fmaxf(cm, __shfl_xor(cm, 16, 64));
        cm = fmaxf(cm, __shfl_xor(cm, 32, 64));
        const float mNew = fmaxf(mrun, cm);

        float psum = 0.f;
        #pragma unroll
        for (int mt = 0; mt < 4; ++mt) {
            const float p0 = exp2f(sacc[mt][0] - mNew);
            const float p1 = exp2f(sacc[mt][1] - mNew);
            const float p2 = exp2f(sacc[mt][2] - mNew);
            const float p3 = exp2f(sacc[mt][3] - mNew);
            psum += (p0 + p1) + (p2 + p3);
            ushort4 pk;
            pk.x = f2bf(p0); pk.y = f2bf(p1); pk.z = f2bf(p2); pk.w = f2bf(p3);
            *(ushort4*)&Ps[w][lo][16 * mt + 4 * q4] = pk;
        }
        psum += __shfl_xor(psum, 16, 64);
        psum += __shfl_xor(psum, 32, 64);

        const float alpha = exp2f(mrun - mNew);
        lrun = lrun * alpha + psum;
        mrun = mNew;
        #pragma unroll
        for (int mt = 0; mt < 4; ++mt) {
            oacc[mt][0] *= alpha; oacc[mt][1] *= alpha;
            oacc[mt][2] *= alpha; oacc[mt][3] *= alpha;
        }

        const bf16x8 bp0 = *(const bf16x8*)&Ps[w][lo][8 * q4];
        const bf16x8 bp1 = *(const bf16x8*)&Ps[w][lo][32 + 8 * q4];
        #pragma unroll
        for (int mt = 0; mt < 4; ++mt) {
            const bf16x8 av0 = *(const bf16x8*)&Vs[16 * mt + lo][8 * q4];
            const bf16x8 av1 = *(const bf16x8*)&Vs[16 * mt + lo][32 + 8 * q4];
            oacc[mt] = __builtin_amdgcn_mfma_f32_16x16x32_bf16(av0, bp0, oacc[mt], 0, 0, 0);
            oacc[mt] = __builtin_amdgcn_mfma_f32_16x16x32_bf16(av1, bp1, oacc[mt], 0, 0, 0);
        }
    }

    // epilogue: O^T[d][t] -> attnT[b][t0+16w+lo][h*64 + d] bf16
    const float inv = 1.0f / lrun;
    unsigned short* op = attnT + ((size_t)(b * 1024 + t0 + 16 * w + lo)) * 512 + h * 64;
    #pragma unroll
    for (int mt = 0; mt < 4; ++mt) {
        ushort4 pk;
        pk.x = f2bf(oacc[mt][0] * inv);
        pk.y = f2bf(oacc[mt][1] * inv);
        pk.z = f2bf(oacc[mt][2] * inv);
        pk.w = f2bf(oacc[mt][3] * inv);
        *(ushort4*)(op + 16 * mt + 4 * q4) = pk;
    }
}

// ---------------------------------------------------------------------------
// Kernel 5: proj GEMM + bias + residual, fp32 out.
// ---------------------------------------------------------------------------
__global__ __launch_bounds__(256)
void proj_mfma_kernel(const unsigned short* __restrict__ wpb,
                      const unsigned short* __restrict__ attnT,
                      const float* __restrict__ proj_b,
                      const float* __restrict__ x,
                      float* __restrict__ out) {
    __shared__ __align__(16) unsigned short As[128 * 32];
    __shared__ __align__(16) unsigned short Bs[128 * 32];
    const int batch = blockIdx.z;
    const int mBase = blockIdx.y * 128, nBase = blockIdx.x * 128;

    f32x4 acc[4][4] = {};
    mfma_gemm_core((const char*)(wpb + (size_t)mBase * 512),
                   (const char*)(attnT + ((size_t)batch * 1024 + nBase) * 512),
                   As, Bs, acc);

    const int tid = threadIdx.x;
    const int w = tid >> 6, lane = tid & 63;
    const int lo = lane & 15, q4 = lane >> 4;
    const int wm = w >> 1, wn = w & 1;
    const float* xb = x + (size_t)batch * 524288;
    float* ob = out + (size_t)batch * 524288;

    #pragma unroll
    for (int mi = 0; mi < 4; ++mi) {
        const int m0 = mBase + wm * 64 + mi * 16 + q4 * 4;
        const float4 bq = *(const float4*)(proj_b + m0);
        #pragma unroll
        for (int ni = 0; ni < 4; ++ni) {
            const int t = nBase + wn * 64 + ni * 16 + lo;
            const size_t o0 = (size_t)m0 * 1024 + t;
            ob[o0]          = acc[mi][ni][0] + bq.x + xb[o0];
            ob[o0 + 1024]   = acc[mi][ni][1] + bq.y + xb[o0 + 1024];
            ob[o0 + 2048]   = acc[mi][ni][2] + bq.z + xb[o0 + 2048];
            ob[o0 + 3072]   = acc[mi][ni][3] + bq.w + xb[o0 + 3072];
        }
    }
}

// ---------------------------------------------------------------------------
// Launch
// ---------------------------------------------------------------------------
extern "C" void kernel_launch(void* const* d_in, const int* in_sizes, int n_in,
                              void* d_out, int out_size, void* d_ws, size_t ws_size,
                              hipStream_t stream) {
    const float* x        = (const float*)d_in[0];
    const float* gn_gamma = (const float*)d_in[1];
    const float* gn_beta  = (const float*)d_in[2];
    const float* qkv_w    = (const float*)d_in[3];
    const float* qkv_b    = (const float*)d_in[4];
    const float* proj_w   = (const float*)d_in[5];
    const float* proj_b   = (const float*)d_in[6];
    float* out = (float*)d_out;

    // workspace layout (~82 MiB)
    char* wsc = (char*)d_ws;
    unsigned short* xnT   = (unsigned short*)(wsc);              // 16 MiB [b][t][c]
    unsigned short* Qt    = (unsigned short*)(wsc + 16777216);   // 16 MiB [bh][t][d]
    unsigned short* Kt    = (unsigned short*)(wsc + 33554432);   // 16 MiB [bh][t][d]
    unsigned short* Vb    = (unsigned short*)(wsc + 50331648);   // 16 MiB [b][d'][t]
    unsigned short* attnT = (unsigned short*)(wsc + 67108864);   // 16 MiB [b][t][c]
    unsigned short* wqb   = (unsigned short*)(wsc + 83886080);   // 1.5 MiB (wpb follows)
    unsigned short* wpb   = wqb + 786432;                        // 0.5 MiB

    // 1. GroupNorm -> xnT bf16
    groupnorm_t_kernel<<<B * NUM_GROUPS, 256, 0, stream>>>(x, gn_gamma, gn_beta, xnT);

    // 2. Weights -> bf16
    wconv_kernel<<<1024, 256, 0, stream>>>(qkv_w, proj_w, wqb);

    // 3. QKV MFMA GEMM (writes Qt, Kt, Vb directly)
    {
        dim3 grid(HW / 128, (3 * C) / 128, B);
        qkv_mfma_kernel<<<grid, 256, 0, stream>>>(wqb, xnT, qkv_b, Qt, Kt, Vb);
    }

    // 4. MFMA flash attention -> attnT bf16
    {
        dim3 grid(B * NUM_HEADS, HW / 64);
        attn_mfma_kernel<<<grid, 256, 0, stream>>>(Qt, Kt, Vb, attnT);
    }

    // 5. Proj MFMA GEMM + bias + residual -> fp32 out
    {
        dim3 grid(HW / 128, C / 128, B);
        proj_mfma_kernel<<<grid, 256, 0, stream>>>(wpb, attnT, proj_b, x, out);
    }
}

// Round 5
// 247.997 us; speedup vs baseline: 5.8620x; 1.0688x over previous
//
#include <hip/hip_runtime.h>
#include <math.h>

#define NUM_HEADS 8
#define NUM_GROUPS 32
#define EPS 1e-5f

constexpr int B  = 16;
constexpr int C  = 512;
constexpr int HW = 1024;   // 32*32
constexpr int HD = 64;

typedef short bf16x8 __attribute__((ext_vector_type(8)));
typedef float f32x4  __attribute__((ext_vector_type(4)));

#define QSCALE 0.1803368801111f  /* 0.125 * log2(e): softmax done in exp2 space */

__device__ inline unsigned short f2bf(float f) {
    union { float f; unsigned int u; } v; v.f = f;
    unsigned int r = (v.u + 0x7FFFu + ((v.u >> 16) & 1u)) >> 16;
    return (unsigned short)r;
}

// async global->LDS, 16B per lane. LDS dest = wave-uniform base + lane*16.
__device__ __forceinline__ void gld_lds16(void* lds, const void* g) {
    __builtin_amdgcn_global_load_lds(
        (const __attribute__((address_space(1))) void*)g,
        (__attribute__((address_space(3))) void*)lds, 16, 0, 0);
}

// ---------------------------------------------------------------------------
// Kernel 1: GroupNorm -> xnT bf16 [b][t=1024][c=512] (c-contiguous).
// ---------------------------------------------------------------------------
__global__ __launch_bounds__(256)
void groupnorm_t_kernel(const float* __restrict__ x,
                        const float* __restrict__ gamma,
                        const float* __restrict__ beta,
                        unsigned short* __restrict__ xnT) {
    const int bg = blockIdx.x;
    const int b = bg >> 5, g = bg & 31;
    const size_t base = ((size_t)b * C + (size_t)g * 16) * HW;
    const float4* xp4 = (const float4*)(x + base);

    float sum = 0.f, sumsq = 0.f;
    for (int i = threadIdx.x; i < 4096; i += 256) {
        float4 v = xp4[i];
        sum += v.x + v.y + v.z + v.w;
        sumsq += v.x * v.x + v.y * v.y + v.z * v.z + v.w * v.w;
    }
    #pragma unroll
    for (int off = 32; off > 0; off >>= 1) {
        sum   += __shfl_down(sum, off, 64);
        sumsq += __shfl_down(sumsq, off, 64);
    }
    __shared__ float s_sum[4], s_sq[4];
    const int wid = threadIdx.x >> 6, lane = threadIdx.x & 63;
    if (lane == 0) { s_sum[wid] = sum; s_sq[wid] = sumsq; }
    __syncthreads();
    const float tsum = s_sum[0] + s_sum[1] + s_sum[2] + s_sum[3];
    const float tsq  = s_sq[0] + s_sq[1] + s_sq[2] + s_sq[3];
    const float mean = tsum * (1.0f / 16384.f);
    const float var  = tsq * (1.0f / 16384.f) - mean * mean;
    const float rstd = rsqrtf(var + EPS);

    float ga[16], be[16];
    #pragma unroll
    for (int cl = 0; cl < 16; ++cl) {
        ga[cl] = gamma[g * 16 + cl] * rstd;
        be[cl] = beta[g * 16 + cl] - mean * ga[cl];
    }

    #pragma unroll
    for (int p = 0; p < 4; ++p) {
        const int t = threadIdx.x + p * 256;
        unsigned short pk[16];
        #pragma unroll
        for (int cl = 0; cl < 16; ++cl) {
            const float v = x[base + (size_t)cl * HW + t];
            pk[cl] = f2bf(v * ga[cl] + be[cl]);
        }
        unsigned short* dst = xnT + ((size_t)(b * 1024 + t)) * 512 + g * 16;
        *(uint4*)dst = *(const uint4*)pk;
        *(uint4*)(dst + 8) = *(const uint4*)(pk + 8);
    }
}

// ---------------------------------------------------------------------------
// Kernel 2: weight conversion fp32 -> bf16.
// ---------------------------------------------------------------------------
__global__ __launch_bounds__(256)
void wconv_kernel(const float* __restrict__ qkv_w,
                  const float* __restrict__ proj_w,
                  unsigned short* __restrict__ wqb) {
    const int i = blockIdx.x * 256 + threadIdx.x;   // float4 index
    const int n1 = 786432 / 4;
    const int nt = 1048576 / 4;
    if (i >= nt) return;
    const float4 v = (i < n1) ? ((const float4*)qkv_w)[i]
                              : ((const float4*)proj_w)[i - n1];
    ushort4 r;
    r.x = f2bf(v.x); r.y = f2bf(v.y); r.z = f2bf(v.z); r.w = f2bf(v.w);
    ((ushort4*)wqb)[i] = r;
}

// ---------------------------------------------------------------------------
// Shared MFMA GEMM core (unchanged from round 4).
// ---------------------------------------------------------------------------
__device__ __forceinline__ void mfma_gemm_core(const char* __restrict__ Ab,
                                               const char* __restrict__ Bb,
                                               unsigned short* As,
                                               unsigned short* Bs,
                                               f32x4 acc[4][4]) {
    const int tid = threadIdx.x;
    const int w = tid >> 6, lane = tid & 63;
    const int lo = lane & 15, q4 = lane >> 4;
    const int wm = w >> 1, wn = w & 1;
    const int lrow = lane >> 2, lkc = lane & 3;

    for (int k0 = 0; k0 < 512; k0 += 32) {
        __syncthreads();
        #pragma unroll
        for (int i = 0; i < 2; ++i) {
            const int row = w * 32 + i * 16 + lrow;
            const int kc = lkc ^ ((row >> 1) & 3);   // swizzle k-chunk
            const size_t goff = (size_t)row * 1024 + k0 * 2 + kc * 16;
            gld_lds16((char*)As + w * 2048 + i * 1024, Ab + goff);
            gld_lds16((char*)Bs + w * 2048 + i * 1024, Bb + goff);
        }
        __syncthreads();

        bf16x8 af[4], bfr[4];
        #pragma unroll
        for (int i = 0; i < 4; ++i) {
            const int ra = wm * 64 + i * 16 + lo;
            af[i]  = *(const bf16x8*)(As + ra * 32 + (q4 ^ ((ra >> 1) & 3)) * 8);
            const int rb = wn * 64 + i * 16 + lo;
            bfr[i] = *(const bf16x8*)(Bs + rb * 32 + (q4 ^ ((rb >> 1) & 3)) * 8);
        }
        #pragma unroll
        for (int mi = 0; mi < 4; ++mi)
            #pragma unroll
            for (int ni = 0; ni < 4; ++ni)
                acc[mi][ni] = __builtin_amdgcn_mfma_f32_16x16x32_bf16(
                    af[mi], bfr[ni], acc[mi][ni], 0, 0, 0);
    }
}

// ---------------------------------------------------------------------------
// Kernel 3: QKV projection GEMM (unchanged from round 4).
// ---------------------------------------------------------------------------
__global__ __launch_bounds__(256)
void qkv_mfma_kernel(const unsigned short* __restrict__ wqb,
                     const unsigned short* __restrict__ xnT,
                     const float* __restrict__ qkv_b,
                     unsigned short* __restrict__ Qt,
                     unsigned short* __restrict__ Kt,
                     unsigned short* __restrict__ Vb) {
    __shared__ __align__(16) unsigned short As[128 * 32];
    __shared__ __align__(16) unsigned short Bs[128 * 32];
    const int batch = blockIdx.z;
    const int mBase = blockIdx.y * 128, nBase = blockIdx.x * 128;

    f32x4 acc[4][4] = {};
    mfma_gemm_core((const char*)(wqb + (size_t)mBase * 512),
                   (const char*)(xnT + ((size_t)batch * 1024 + nBase) * 512),
                   As, Bs, acc);

    const int tid = threadIdx.x;
    const int w = tid >> 6, lane = tid & 63;
    const int lo = lane & 15, q4 = lane >> 4;
    const int wm = w >> 1, wn = w & 1;
    const int mw = mBase + wm * 64;          // head-aligned 64-row chunk
    const int tb = nBase + wn * 64;

    if (mw < 1024) {
        const bool isQ = mw < 512;
        const int head = (mw >> 6) & 7;
        unsigned short* dst = (isQ ? Qt : Kt) + (((size_t)batch * 8 + head) << 16);
        const float sc = isQ ? QSCALE : 1.0f;
        #pragma unroll
        for (int mi = 0; mi < 4; ++mi) {
            const float4 bq = *(const float4*)(qkv_b + mw + mi * 16 + q4 * 4);
            #pragma unroll
            for (int ni = 0; ni < 4; ++ni) {
                const int t = tb + ni * 16 + lo;
                ushort4 pk;
                pk.x = f2bf((acc[mi][ni][0] + bq.x) * sc);
                pk.y = f2bf((acc[mi][ni][1] + bq.y) * sc);
                pk.z = f2bf((acc[mi][ni][2] + bq.z) * sc);
                pk.w = f2bf((acc[mi][ni][3] + bq.w) * sc);
                *(ushort4*)(dst + (size_t)t * 64 + mi * 16 + q4 * 4) = pk;
            }
        }
    } else {
        unsigned short* dst = Vb + (size_t)batch * 524288 + (size_t)(mw - 1024) * 1024;
        #pragma unroll
        for (int mi = 0; mi < 4; ++mi) {
            const float4 bq = *(const float4*)(qkv_b + mw + mi * 16 + q4 * 4);
            #pragma unroll
            for (int ni = 0; ni < 4; ++ni) {
                const int t = tb + ni * 16 + lo;
                dst[(size_t)(mi * 16 + q4 * 4 + 0) * 1024 + t] = f2bf(acc[mi][ni][0] + bq.x);
                dst[(size_t)(mi * 16 + q4 * 4 + 1) * 1024 + t] = f2bf(acc[mi][ni][1] + bq.y);
                dst[(size_t)(mi * 16 + q4 * 4 + 2) * 1024 + t] = f2bf(acc[mi][ni][2] + bq.z);
                dst[(size_t)(mi * 16 + q4 * 4 + 3) * 1024 + t] = f2bf(acc[mi][ni][3] + bq.w);
            }
        }
    }
}

// ---------------------------------------------------------------------------
// Kernel 4: MFMA flash attention, 256 queries/block, no online rescale.
// Wave w owns t in [tBase+64w, +64). Q frags + O acc in registers.
// K/V chunks double-buffered in LDS (XOR-swizzled 16B chunks); P per-wave LDS.
// exp2 softmax unnormalized (bounded scores), single 1/l at the end.
// ---------------------------------------------------------------------------
__global__ __launch_bounds__(256, 2)
void attn_mfma_kernel(const unsigned short* __restrict__ Qt,
                      const unsigned short* __restrict__ Kt,
                      const unsigned short* __restrict__ Vb,
                      unsigned short* __restrict__ attnT) {
    const int bh = blockIdx.x;
    const int b = bh >> 3, h = bh & 7;
    const int tBase = blockIdx.y * 256;
    const int tid = threadIdx.x;
    const int w = tid >> 6, lane = tid & 63;
    const int lo = lane & 15, q4 = lane >> 4;
    const int xr = lo & 7;                    // row XOR for swizzle

    __shared__ __align__(16) unsigned short Ks[2][64 * 64];  // [s][d], swizzled
    __shared__ __align__(16) unsigned short Vs[2][64 * 64];  // [d][s], swizzled
    __shared__ __align__(16) unsigned short Ps[4][64 * 64];  // per-wave [t][s], swizzled

    const unsigned short* Kp = Kt + ((size_t)bh << 16);
    const unsigned short* Vp = Vb + ((size_t)b * 512 + h * 64) * 1024;

    // persistent Q B-frags: qf[nt][kh], t = tBase+64w+16nt+lo, d = 32kh+8q4+j
    bf16x8 qf[4][2];
    {
        const unsigned short* Qp = Qt + ((size_t)bh * 1024 + tBase + 64 * w) * 64;
        #pragma unroll
        for (int nt = 0; nt < 4; ++nt) {
            qf[nt][0] = *(const bf16x8*)(Qp + (size_t)(16 * nt + lo) * 64 + 8 * q4);
            qf[nt][1] = *(const bf16x8*)(Qp + (size_t)(16 * nt + lo) * 64 + 32 + 8 * q4);
        }
    }

    // staging lambda: wave w stages rows 16w..16w+15 of K and V chunks
    const int rl = lane >> 3, p8 = lane & 7;
    auto stage = [&](unsigned short* Kd, unsigned short* Vd, int s0) {
        #pragma unroll
        for (int cc = 0; cc < 2; ++cc) {
            const int r = 16 * w + 8 * cc + rl;
            const int j = p8 ^ (r & 7);
            gld_lds16(Kd + (16 * w + 8 * cc) * 64, Kp + (size_t)(s0 + r) * 64 + j * 8);
            gld_lds16(Vd + (16 * w + 8 * cc) * 64, Vp + (size_t)r * 1024 + s0 + j * 8);
        }
    };

    f32x4 oacc[4][4] = {};
    float lrun[4] = {0.f, 0.f, 0.f, 0.f};
    unsigned short* Pw = Ps[w];

    stage(Ks[0], Vs[0], 0);

    for (int i = 0; i < 16; ++i) {
        __syncthreads();   // drains stage(i)'s vmcnt; protects buffer reuse
        if (i < 15) stage(Ks[(i + 1) & 1], Vs[(i + 1) & 1], (i + 1) * 64);
        const unsigned short* Kcur = Ks[i & 1];
        const unsigned short* Vcur = Vs[i & 1];

        // ---- S^T = K^T Q : sacc[mt][nt], m=s, n=t ----
        f32x4 sacc[4][4] = {};
        #pragma unroll
        for (int mt = 0; mt < 4; ++mt) {
            const unsigned short* kr = Kcur + (16 * mt + lo) * 64;
            const bf16x8 a0 = *(const bf16x8*)(kr + ((q4    ) ^ xr) * 8);
            const bf16x8 a1 = *(const bf16x8*)(kr + ((q4 + 4) ^ xr) * 8);
            #pragma unroll
            for (int nt = 0; nt < 4; ++nt) {
                sacc[mt][nt] = __builtin_amdgcn_mfma_f32_16x16x32_bf16(a0, qf[nt][0], sacc[mt][nt], 0, 0, 0);
                sacc[mt][nt] = __builtin_amdgcn_mfma_f32_16x16x32_bf16(a1, qf[nt][1], sacc[mt][nt], 0, 0, 0);
            }
        }

        // ---- P = exp2(S), accumulate l, pack to LDS (swizzled [t][s]) ----
        #pragma unroll
        for (int nt = 0; nt < 4; ++nt) {
            float ps = 0.f;
            const int t = 16 * nt + lo;
            #pragma unroll
            for (int mt = 0; mt < 4; ++mt) {
                const f32x4 s = sacc[mt][nt];
                const float p0 = exp2f(s[0]);
                const float p1 = exp2f(s[1]);
                const float p2 = exp2f(s[2]);
                const float p3 = exp2f(s[3]);
                ps += (p0 + p1) + (p2 + p3);
                ushort4 pk;
                pk.x = f2bf(p0); pk.y = f2bf(p1); pk.z = f2bf(p2); pk.w = f2bf(p3);
                const int sc = 2 * mt + (q4 >> 1);          // s-chunk of s=16mt+4q4
                *(ushort4*)(Pw + t * 64 + ((sc ^ xr) * 8) + 4 * (q4 & 1)) = pk;
            }
            lrun[nt] += ps;
        }

        // ---- O^T += V P^T : m=d, n=t, k=s (same-wave LDS RAW, no barrier) ----
        bf16x8 bp[4][2];
        #pragma unroll
        for (int nt = 0; nt < 4; ++nt) {
            const unsigned short* pr = Pw + (16 * nt + lo) * 64;
            bp[nt][0] = *(const bf16x8*)(pr + ((q4    ) ^ xr) * 8);
            bp[nt][1] = *(const bf16x8*)(pr + ((q4 + 4) ^ xr) * 8);
        }
        #pragma unroll
        for (int mt = 0; mt < 4; ++mt) {
            const unsigned short* vr = Vcur + (16 * mt + lo) * 64;
            const bf16x8 v0 = *(const bf16x8*)(vr + ((q4    ) ^ xr) * 8);
            const bf16x8 v1 = *(const bf16x8*)(vr + ((q4 + 4) ^ xr) * 8);
            #pragma unroll
            for (int nt = 0; nt < 4; ++nt) {
                oacc[mt][nt] = __builtin_amdgcn_mfma_f32_16x16x32_bf16(v0, bp[nt][0], oacc[mt][nt], 0, 0, 0);
                oacc[mt][nt] = __builtin_amdgcn_mfma_f32_16x16x32_bf16(v1, bp[nt][1], oacc[mt][nt], 0, 0, 0);
            }
        }
    }

    // ---- epilogue: reduce l over q4 groups, write attnT[b][t][h*64+d] ----
    #pragma unroll
    for (int nt = 0; nt < 4; ++nt) {
        float lt = lrun[nt];
        lt += __shfl_xor(lt, 16, 64);
        lt += __shfl_xor(lt, 32, 64);
        const float inv = 1.0f / lt;
        const int t = tBase + 64 * w + 16 * nt + lo;
        unsigned short* op = attnT + ((size_t)(b * 1024 + t)) * 512 + h * 64;
        #pragma unroll
        for (int mt = 0; mt < 4; ++mt) {
            ushort4 pk;
            pk.x = f2bf(oacc[mt][nt][0] * inv);
            pk.y = f2bf(oacc[mt][nt][1] * inv);
            pk.z = f2bf(oacc[mt][nt][2] * inv);
            pk.w = f2bf(oacc[mt][nt][3] * inv);
            *(ushort4*)(op + 16 * mt + 4 * q4) = pk;
        }
    }
}

// ---------------------------------------------------------------------------
// Kernel 5: proj GEMM + bias + residual, fp32 out (unchanged from round 4).
// ---------------------------------------------------------------------------
__global__ __launch_bounds__(256)
void proj_mfma_kernel(const unsigned short* __restrict__ wpb,
                      const unsigned short* __restrict__ attnT,
                      const float* __restrict__ proj_b,
                      const float* __restrict__ x,
                      float* __restrict__ out) {
    __shared__ __align__(16) unsigned short As[128 * 32];
    __shared__ __align__(16) unsigned short Bs[128 * 32];
    const int batch = blockIdx.z;
    const int mBase = blockIdx.y * 128, nBase = blockIdx.x * 128;

    f32x4 acc[4][4] = {};
    mfma_gemm_core((const char*)(wpb + (size_t)mBase * 512),
                   (const char*)(attnT + ((size_t)batch * 1024 + nBase) * 512),
                   As, Bs, acc);

    const int tid = threadIdx.x;
    const int w = tid >> 6, lane = tid & 63;
    const int lo = lane & 15, q4 = lane >> 4;
    const int wm = w >> 1, wn = w & 1;
    const float* xb = x + (size_t)batch * 524288;
    float* ob = out + (size_t)batch * 524288;

    #pragma unroll
    for (int mi = 0; mi < 4; ++mi) {
        const int m0 = mBase + wm * 64 + mi * 16 + q4 * 4;
        const float4 bq = *(const float4*)(proj_b + m0);
        #pragma unroll
        for (int ni = 0; ni < 4; ++ni) {
            const int t = nBase + wn * 64 + ni * 16 + lo;
            const size_t o0 = (size_t)m0 * 1024 + t;
            ob[o0]          = acc[mi][ni][0] + bq.x + xb[o0];
            ob[o0 + 1024]   = acc[mi][ni][1] + bq.y + xb[o0 + 1024];
            ob[o0 + 2048]   = acc[mi][ni][2] + bq.z + xb[o0 + 2048];
            ob[o0 + 3072]   = acc[mi][ni][3] + bq.w + xb[o0 + 3072];
        }
    }
}

// ---------------------------------------------------------------------------
// Launch
// ---------------------------------------------------------------------------
extern "C" void kernel_launch(void* const* d_in, const int* in_sizes, int n_in,
                              void* d_out, int out_size, void* d_ws, size_t ws_size,
                              hipStream_t stream) {
    const float* x        = (const float*)d_in[0];
    const float* gn_gamma = (const float*)d_in[1];
    const float* gn_beta  = (const float*)d_in[2];
    const float* qkv_w    = (const float*)d_in[3];
    const float* qkv_b    = (const float*)d_in[4];
    const float* proj_w   = (const float*)d_in[5];
    const float* proj_b   = (const float*)d_in[6];
    float* out = (float*)d_out;

    // workspace layout (~82 MiB)
    char* wsc = (char*)d_ws;
    unsigned short* xnT   = (unsigned short*)(wsc);              // 16 MiB [b][t][c]
    unsigned short* Qt    = (unsigned short*)(wsc + 16777216);   // 16 MiB [bh][t][d]
    unsigned short* Kt    = (unsigned short*)(wsc + 33554432);   // 16 MiB [bh][t][d]
    unsigned short* Vb    = (unsigned short*)(wsc + 50331648);   // 16 MiB [b][d'][t]
    unsigned short* attnT = (unsigned short*)(wsc + 67108864);   // 16 MiB [b][t][c]
    unsigned short* wqb   = (unsigned short*)(wsc + 83886080);   // 1.5 MiB (wpb follows)
    unsigned short* wpb   = wqb + 786432;                        // 0.5 MiB

    // 1. GroupNorm -> xnT bf16
    groupnorm_t_kernel<<<B * NUM_GROUPS, 256, 0, stream>>>(x, gn_gamma, gn_beta, xnT);

    // 2. Weights -> bf16
    wconv_kernel<<<1024, 256, 0, stream>>>(qkv_w, proj_w, wqb);

    // 3. QKV MFMA GEMM (writes Qt, Kt, Vb directly)
    {
        dim3 grid(HW / 128, (3 * C) / 128, B);
        qkv_mfma_kernel<<<grid, 256, 0, stream>>>(wqb, xnT, qkv_b, Qt, Kt, Vb);
    }

    // 4. MFMA flash attention -> attnT bf16 (256 queries per block)
    {
        dim3 grid(B * NUM_HEADS, HW / 256);
        attn_mfma_kernel<<<grid, 256, 0, stream>>>(Qt, Kt, Vb, attnT);
    }

    // 5. Proj MFMA GEMM + bias + residual -> fp32 out
    {
        dim3 grid(HW / 128, C / 128, B);
        proj_mfma_kernel<<<grid, 256, 0, stream>>>(wpb, attnT, proj_b, x, out);
    }
}

// Round 6
// 238.972 us; speedup vs baseline: 6.0834x; 1.0378x over previous
//
#include <hip/hip_runtime.h>
#include <math.h>

#define NUM_HEADS 8
#define NUM_GROUPS 32
#define EPS 1e-5f

constexpr int B  = 16;
constexpr int C  = 512;
constexpr int HW = 1024;   // 32*32
constexpr int HD = 64;

typedef short bf16x8 __attribute__((ext_vector_type(8)));
typedef float f32x4  __attribute__((ext_vector_type(4)));

#define QSCALE 0.1803368801111f  /* 0.125 * log2(e): softmax done in exp2 space */

__device__ inline unsigned short f2bf(float f) {
    union { float f; unsigned int u; } v; v.f = f;
    unsigned int r = (v.u + 0x7FFFu + ((v.u >> 16) & 1u)) >> 16;
    return (unsigned short)r;
}

// pack two fp32 -> bf16 pair by truncation, single v_perm_b32
__device__ __forceinline__ unsigned int pack_trunc(float lo, float hi) {
    return __builtin_amdgcn_perm(__float_as_uint(hi), __float_as_uint(lo), 0x07060302u);
}

// async global->LDS, 16B per lane. LDS dest = wave-uniform base + lane*16.
__device__ __forceinline__ void gld_lds16(void* lds, const void* g) {
    __builtin_amdgcn_global_load_lds(
        (const __attribute__((address_space(1))) void*)g,
        (__attribute__((address_space(3))) void*)lds, 16, 0, 0);
}

// ---------------------------------------------------------------------------
// Kernel 1: GroupNorm -> xnT bf16 [b][t=1024][c=512]. Single pass: each
// thread keeps its 64 elements (4 t x 16 c) in registers between stats and
// the normalize-write.
// ---------------------------------------------------------------------------
__global__ __launch_bounds__(256)
void groupnorm_t_kernel(const float* __restrict__ x,
                        const float* __restrict__ gamma,
                        const float* __restrict__ beta,
                        unsigned short* __restrict__ xnT) {
    const int bg = blockIdx.x;
    const int b = bg >> 5, g = bg & 31;
    const size_t base = ((size_t)b * C + (size_t)g * 16) * HW;

    float v[4][16];
    float sum = 0.f, sumsq = 0.f;
    #pragma unroll
    for (int p = 0; p < 4; ++p) {
        const int t = threadIdx.x + p * 256;
        #pragma unroll
        for (int cl = 0; cl < 16; ++cl) {
            const float f = x[base + (size_t)cl * HW + t];
            v[p][cl] = f;
            sum += f;
            sumsq += f * f;
        }
    }
    #pragma unroll
    for (int off = 32; off > 0; off >>= 1) {
        sum   += __shfl_down(sum, off, 64);
        sumsq += __shfl_down(sumsq, off, 64);
    }
    __shared__ float s_sum[4], s_sq[4];
    const int wid = threadIdx.x >> 6, lane = threadIdx.x & 63;
    if (lane == 0) { s_sum[wid] = sum; s_sq[wid] = sumsq; }
    __syncthreads();
    const float tsum = s_sum[0] + s_sum[1] + s_sum[2] + s_sum[3];
    const float tsq  = s_sq[0] + s_sq[1] + s_sq[2] + s_sq[3];
    const float mean = tsum * (1.0f / 16384.f);
    const float var  = tsq * (1.0f / 16384.f) - mean * mean;
    const float rstd = rsqrtf(var + EPS);

    float ga[16], be[16];
    #pragma unroll
    for (int cl = 0; cl < 16; ++cl) {
        ga[cl] = gamma[g * 16 + cl] * rstd;
        be[cl] = beta[g * 16 + cl] - mean * ga[cl];
    }

    #pragma unroll
    for (int p = 0; p < 4; ++p) {
        const int t = threadIdx.x + p * 256;
        unsigned short pk[16];
        #pragma unroll
        for (int cl = 0; cl < 16; ++cl)
            pk[cl] = f2bf(v[p][cl] * ga[cl] + be[cl]);
        unsigned short* dst = xnT + ((size_t)(b * 1024 + t)) * 512 + g * 16;
        *(uint4*)dst = *(const uint4*)pk;
        *(uint4*)(dst + 8) = *(const uint4*)(pk + 8);
    }
}

// ---------------------------------------------------------------------------
// Kernel 2: weight conversion fp32 -> bf16.
// ---------------------------------------------------------------------------
__global__ __launch_bounds__(256)
void wconv_kernel(const float* __restrict__ qkv_w,
                  const float* __restrict__ proj_w,
                  unsigned short* __restrict__ wqb) {
    const int i = blockIdx.x * 256 + threadIdx.x;   // float4 index
    const int n1 = 786432 / 4;
    const int nt = 1048576 / 4;
    if (i >= nt) return;
    const float4 v = (i < n1) ? ((const float4*)qkv_w)[i]
                              : ((const float4*)proj_w)[i - n1];
    ushort4 r;
    r.x = f2bf(v.x); r.y = f2bf(v.y); r.z = f2bf(v.z); r.w = f2bf(v.w);
    ((ushort4*)wqb)[i] = r;
}

// ---------------------------------------------------------------------------
// Shared MFMA GEMM core (unchanged).
// ---------------------------------------------------------------------------
__device__ __forceinline__ void mfma_gemm_core(const char* __restrict__ Ab,
                                               const char* __restrict__ Bb,
                                               unsigned short* As,
                                               unsigned short* Bs,
                                               f32x4 acc[4][4]) {
    const int tid = threadIdx.x;
    const int w = tid >> 6, lane = tid & 63;
    const int lo = lane & 15, q4 = lane >> 4;
    const int wm = w >> 1, wn = w & 1;
    const int lrow = lane >> 2, lkc = lane & 3;

    for (int k0 = 0; k0 < 512; k0 += 32) {
        __syncthreads();
        #pragma unroll
        for (int i = 0; i < 2; ++i) {
            const int row = w * 32 + i * 16 + lrow;
            const int kc = lkc ^ ((row >> 1) & 3);   // swizzle k-chunk
            const size_t goff = (size_t)row * 1024 + k0 * 2 + kc * 16;
            gld_lds16((char*)As + w * 2048 + i * 1024, Ab + goff);
            gld_lds16((char*)Bs + w * 2048 + i * 1024, Bb + goff);
        }
        __syncthreads();

        bf16x8 af[4], bfr[4];
        #pragma unroll
        for (int i = 0; i < 4; ++i) {
            const int ra = wm * 64 + i * 16 + lo;
            af[i]  = *(const bf16x8*)(As + ra * 32 + (q4 ^ ((ra >> 1) & 3)) * 8);
            const int rb = wn * 64 + i * 16 + lo;
            bfr[i] = *(const bf16x8*)(Bs + rb * 32 + (q4 ^ ((rb >> 1) & 3)) * 8);
        }
        #pragma unroll
        for (int mi = 0; mi < 4; ++mi)
            #pragma unroll
            for (int ni = 0; ni < 4; ++ni)
                acc[mi][ni] = __builtin_amdgcn_mfma_f32_16x16x32_bf16(
                    af[mi], bfr[ni], acc[mi][ni], 0, 0, 0);
    }
}

// ---------------------------------------------------------------------------
// Kernel 3: QKV projection GEMM. Q/K epilogue: direct ushort4 stores (as
// before). V epilogue: LDS transpose (reusing GEMM staging LDS) -> coalesced
// uint4 stores into Vb[b][d][t].
// ---------------------------------------------------------------------------
__global__ __launch_bounds__(256)
void qkv_mfma_kernel(const unsigned short* __restrict__ wqb,
                     const unsigned short* __restrict__ xnT,
                     const float* __restrict__ qkv_b,
                     unsigned short* __restrict__ Qt,
                     unsigned short* __restrict__ Kt,
                     unsigned short* __restrict__ Vb) {
    __shared__ __align__(16) unsigned short SMEM[8192];  // As | Bs, reused by V epilogue
    unsigned short* As = SMEM;
    unsigned short* Bs = SMEM + 4096;
    const int batch = blockIdx.z;
    const int mBase = blockIdx.y * 128, nBase = blockIdx.x * 128;

    f32x4 acc[4][4] = {};
    mfma_gemm_core((const char*)(wqb + (size_t)mBase * 512),
                   (const char*)(xnT + ((size_t)batch * 1024 + nBase) * 512),
                   As, Bs, acc);

    const int tid = threadIdx.x;
    const int w = tid >> 6, lane = tid & 63;
    const int lo = lane & 15, q4 = lane >> 4;
    const int wm = w >> 1, wn = w & 1;
    const int mw = mBase + wm * 64;          // head-aligned 64-row chunk
    const int tb = nBase + wn * 64;

    __syncthreads();   // all waves done with GEMM LDS (uniform: every thread reaches)

    if (mw < 1024) {
        const bool isQ = mw < 512;
        const int head = (mw >> 6) & 7;
        unsigned short* dst = (isQ ? Qt : Kt) + (((size_t)batch * 8 + head) << 16);
        const float sc = isQ ? QSCALE : 1.0f;
        #pragma unroll
        for (int mi = 0; mi < 4; ++mi) {
            const float4 bq = *(const float4*)(qkv_b + mw + mi * 16 + q4 * 4);
            #pragma unroll
            for (int ni = 0; ni < 4; ++ni) {
                const int t = tb + ni * 16 + lo;
                ushort4 pk;
                pk.x = f2bf((acc[mi][ni][0] + bq.x) * sc);
                pk.y = f2bf((acc[mi][ni][1] + bq.y) * sc);
                pk.z = f2bf((acc[mi][ni][2] + bq.z) * sc);
                pk.w = f2bf((acc[mi][ni][3] + bq.w) * sc);
                *(ushort4*)(dst + (size_t)t * 64 + mi * 16 + q4 * 4) = pk;
            }
        }
    } else {
        // V: wave tile is 64d x 64t; transpose via per-wave 4KB LDS region in
        // two 32-row passes, then coalesced uint4 stores (8 rows x 128B each).
        unsigned short* T = SMEM + w * 2048;         // 32 x 64 shorts
        unsigned short* Vrow = Vb + (size_t)batch * 524288 + (size_t)(mw - 1024) * 1024 + tb;
        const int rl8 = lane >> 3, c8 = lane & 7;
        #pragma unroll
        for (int p = 0; p < 2; ++p) {
            #pragma unroll
            for (int mi2 = 0; mi2 < 2; ++mi2) {
                const int mi = 2 * p + mi2;
                const float4 bq = *(const float4*)(qkv_b + mw + mi * 16 + q4 * 4);
                const int dl = mi2 * 16 + q4 * 4;
                #pragma unroll
                for (int ni = 0; ni < 4; ++ni) {
                    const int tl = ni * 16 + lo;
                    T[(dl + 0) * 64 + tl] = f2bf(acc[mi][ni][0] + bq.x);
                    T[(dl + 1) * 64 + tl] = f2bf(acc[mi][ni][1] + bq.y);
                    T[(dl + 2) * 64 + tl] = f2bf(acc[mi][ni][2] + bq.z);
                    T[(dl + 3) * 64 + tl] = f2bf(acc[mi][ni][3] + bq.w);
                }
            }
            // same-wave LDS RAW (compiler inserts lgkmcnt); no barrier needed
            #pragma unroll
            for (int i = 0; i < 4; ++i) {
                const int dl = i * 8 + rl8;
                const uint4 val = *(const uint4*)&T[dl * 64 + c8 * 8];
                *(uint4*)(Vrow + (size_t)(p * 32 + dl) * 1024 + c8 * 8) = val;
            }
        }
    }
}

// ---------------------------------------------------------------------------
// Kernel 4: MFMA flash attention, 256 queries/block. P packed to bf16 by
// truncation (v_perm_b32), unnormalized exp2 softmax, single 1/l at the end.
// ---------------------------------------------------------------------------
__global__ __launch_bounds__(256, 2)
void attn_mfma_kernel(const unsigned short* __restrict__ Qt,
                      const unsigned short* __restrict__ Kt,
                      const unsigned short* __restrict__ Vb,
                      unsigned short* __restrict__ attnT) {
    const int bh = blockIdx.x;
    const int b = bh >> 3, h = bh & 7;
    const int tBase = blockIdx.y * 256;
    const int tid = threadIdx.x;
    const int w = tid >> 6, lane = tid & 63;
    const int lo = lane & 15, q4 = lane >> 4;
    const int xr = lo & 7;                    // row XOR for swizzle

    __shared__ __align__(16) unsigned short Ks[2][64 * 64];  // [s][d], swizzled
    __shared__ __align__(16) unsigned short Vs[2][64 * 64];  // [d][s], swizzled
    __shared__ __align__(16) unsigned short Ps[4][64 * 64];  // per-wave [t][s], swizzled

    const unsigned short* Kp = Kt + ((size_t)bh << 16);
    const unsigned short* Vp = Vb + ((size_t)b * 512 + h * 64) * 1024;

    // persistent Q B-frags: qf[nt][kh], t = tBase+64w+16nt+lo, d = 32kh+8q4+j
    bf16x8 qf[4][2];
    {
        const unsigned short* Qp = Qt + ((size_t)bh * 1024 + tBase + 64 * w) * 64;
        #pragma unroll
        for (int nt = 0; nt < 4; ++nt) {
            qf[nt][0] = *(const bf16x8*)(Qp + (size_t)(16 * nt + lo) * 64 + 8 * q4);
            qf[nt][1] = *(const bf16x8*)(Qp + (size_t)(16 * nt + lo) * 64 + 32 + 8 * q4);
        }
    }

    // staging: wave w stages rows 16w..16w+15 of K and V chunks
    const int rl = lane >> 3, p8 = lane & 7;
    auto stage = [&](unsigned short* Kd, unsigned short* Vd, int s0) {
        #pragma unroll
        for (int cc = 0; cc < 2; ++cc) {
            const int r = 16 * w + 8 * cc + rl;
            const int j = p8 ^ (r & 7);
            gld_lds16(Kd + (16 * w + 8 * cc) * 64, Kp + (size_t)(s0 + r) * 64 + j * 8);
            gld_lds16(Vd + (16 * w + 8 * cc) * 64, Vp + (size_t)r * 1024 + s0 + j * 8);
        }
    };

    f32x4 oacc[4][4] = {};
    float lrun[4] = {0.f, 0.f, 0.f, 0.f};
    unsigned short* Pw = Ps[w];

    stage(Ks[0], Vs[0], 0);

    for (int i = 0; i < 16; ++i) {
        __syncthreads();   // drains stage(i)'s vmcnt; protects buffer reuse
        if (i < 15) stage(Ks[(i + 1) & 1], Vs[(i + 1) & 1], (i + 1) * 64);
        const unsigned short* Kcur = Ks[i & 1];
        const unsigned short* Vcur = Vs[i & 1];

        // ---- S^T = K^T Q : sacc[mt][nt], m=s, n=t ----
        f32x4 sacc[4][4] = {};
        #pragma unroll
        for (int mt = 0; mt < 4; ++mt) {
            const unsigned short* kr = Kcur + (16 * mt + lo) * 64;
            const bf16x8 a0 = *(const bf16x8*)(kr + ((q4    ) ^ xr) * 8);
            const bf16x8 a1 = *(const bf16x8*)(kr + ((q4 + 4) ^ xr) * 8);
            #pragma unroll
            for (int nt = 0; nt < 4; ++nt) {
                sacc[mt][nt] = __builtin_amdgcn_mfma_f32_16x16x32_bf16(a0, qf[nt][0], sacc[mt][nt], 0, 0, 0);
                sacc[mt][nt] = __builtin_amdgcn_mfma_f32_16x16x32_bf16(a1, qf[nt][1], sacc[mt][nt], 0, 0, 0);
            }
        }

        // ---- P = exp2(S), accumulate l, truncation-pack to LDS ----
        #pragma unroll
        for (int nt = 0; nt < 4; ++nt) {
            float ps = 0.f;
            const int t = 16 * nt + lo;
            #pragma unroll
            for (int mt = 0; mt < 4; ++mt) {
                const f32x4 s = sacc[mt][nt];
                const float p0 = exp2f(s[0]);
                const float p1 = exp2f(s[1]);
                const float p2 = exp2f(s[2]);
                const float p3 = exp2f(s[3]);
                ps += (p0 + p1) + (p2 + p3);
                uint2 pk;
                pk.x = pack_trunc(p0, p1);
                pk.y = pack_trunc(p2, p3);
                const int sc = 2 * mt + (q4 >> 1);          // s-chunk of s=16mt+4q4
                *(uint2*)(Pw + t * 64 + ((sc ^ xr) * 8) + 4 * (q4 & 1)) = pk;
            }
            lrun[nt] += ps;
        }

        // ---- O^T += V P^T : m=d, n=t, k=s (same-wave LDS RAW, no barrier) ----
        bf16x8 bp[4][2];
        #pragma unroll
        for (int nt = 0; nt < 4; ++nt) {
            const unsigned short* pr = Pw + (16 * nt + lo) * 64;
            bp[nt][0] = *(const bf16x8*)(pr + ((q4    ) ^ xr) * 8);
            bp[nt][1] = *(const bf16x8*)(pr + ((q4 + 4) ^ xr) * 8);
        }
        #pragma unroll
        for (int mt = 0; mt < 4; ++mt) {
            const unsigned short* vr = Vcur + (16 * mt + lo) * 64;
            const bf16x8 v0 = *(const bf16x8*)(vr + ((q4    ) ^ xr) * 8);
            const bf16x8 v1 = *(const bf16x8*)(vr + ((q4 + 4) ^ xr) * 8);
            #pragma unroll
            for (int nt = 0; nt < 4; ++nt) {
                oacc[mt][nt] = __builtin_amdgcn_mfma_f32_16x16x32_bf16(v0, bp[nt][0], oacc[mt][nt], 0, 0, 0);
                oacc[mt][nt] = __builtin_amdgcn_mfma_f32_16x16x32_bf16(v1, bp[nt][1], oacc[mt][nt], 0, 0, 0);
            }
        }
    }

    // ---- epilogue: reduce l over q4 groups, write attnT[b][t][h*64+d] ----
    #pragma unroll
    for (int nt = 0; nt < 4; ++nt) {
        float lt = lrun[nt];
        lt += __shfl_xor(lt, 16, 64);
        lt += __shfl_xor(lt, 32, 64);
        const float inv = 1.0f / lt;
        const int t = tBase + 64 * w + 16 * nt + lo;
        unsigned short* op = attnT + ((size_t)(b * 1024 + t)) * 512 + h * 64;
        #pragma unroll
        for (int mt = 0; mt < 4; ++mt) {
            uint2 pk;
            pk.x = pack_trunc(oacc[mt][nt][0] * inv, oacc[mt][nt][1] * inv);
            pk.y = pack_trunc(oacc[mt][nt][2] * inv, oacc[mt][nt][3] * inv);
            *(uint2*)(op + 16 * mt + 4 * q4) = pk;
        }
    }
}

// ---------------------------------------------------------------------------
// Kernel 5: proj GEMM + bias + residual, fp32 out (unchanged).
// ---------------------------------------------------------------------------
__global__ __launch_bounds__(256)
void proj_mfma_kernel(const unsigned short* __restrict__ wpb,
                      const unsigned short* __restrict__ attnT,
                      const float* __restrict__ proj_b,
                      const float* __restrict__ x,
                      float* __restrict__ out) {
    __shared__ __align__(16) unsigned short As[128 * 32];
    __shared__ __align__(16) unsigned short Bs[128 * 32];
    const int batch = blockIdx.z;
    const int mBase = blockIdx.y * 128, nBase = blockIdx.x * 128;

    f32x4 acc[4][4] = {};
    mfma_gemm_core((const char*)(wpb + (size_t)mBase * 512),
                   (const char*)(attnT + ((size_t)batch * 1024 + nBase) * 512),
                   As, Bs, acc);

    const int tid = threadIdx.x;
    const int w = tid >> 6, lane = tid & 63;
    const int lo = lane & 15, q4 = lane >> 4;
    const int wm = w >> 1, wn = w & 1;
    const float* xb = x + (size_t)batch * 524288;
    float* ob = out + (size_t)batch * 524288;

    #pragma unroll
    for (int mi = 0; mi < 4; ++mi) {
        const int m0 = mBase + wm * 64 + mi * 16 + q4 * 4;
        const float4 bq = *(const float4*)(proj_b + m0);
        #pragma unroll
        for (int ni = 0; ni < 4; ++ni) {
            const int t = nBase + wn * 64 + ni * 16 + lo;
            const size_t o0 = (size_t)m0 * 1024 + t;
            ob[o0]          = acc[mi][ni][0] + bq.x + xb[o0];
            ob[o0 + 1024]   = acc[mi][ni][1] + bq.y + xb[o0 + 1024];
            ob[o0 + 2048]   = acc[mi][ni][2] + bq.z + xb[o0 + 2048];
            ob[o0 + 3072]   = acc[mi][ni][3] + bq.w + xb[o0 + 3072];
        }
    }
}

// ---------------------------------------------------------------------------
// Launch
// ---------------------------------------------------------------------------
extern "C" void kernel_launch(void* const* d_in, const int* in_sizes, int n_in,
                              void* d_out, int out_size, void* d_ws, size_t ws_size,
                              hipStream_t stream) {
    const float* x        = (const float*)d_in[0];
    const float* gn_gamma = (const float*)d_in[1];
    const float* gn_beta  = (const float*)d_in[2];
    const float* qkv_w    = (const float*)d_in[3];
    const float* qkv_b    = (const float*)d_in[4];
    const float* proj_w   = (const float*)d_in[5];
    const float* proj_b   = (const float*)d_in[6];
    float* out = (float*)d_out;

    // workspace layout (~86 MiB)
    char* wsc = (char*)d_ws;
    unsigned short* xnT   = (unsigned short*)(wsc);              // 16 MiB [b][t][c]
    unsigned short* Qt    = (unsigned short*)(wsc + 16777216);   // 16 MiB [bh][t][d]
    unsigned short* Kt    = (unsigned short*)(wsc + 33554432);   // 16 MiB [bh][t][d]
    unsigned short* Vb    = (unsigned short*)(wsc + 50331648);   // 16 MiB [b][d'][t]
    unsigned short* attnT = (unsigned short*)(wsc + 67108864);   // 16 MiB [b][t][c]
    unsigned short* wqb   = (unsigned short*)(wsc + 83886080);   // 1.5 MiB (wpb follows)
    unsigned short* wpb   = wqb + 786432;                        // 0.5 MiB

    // 1. GroupNorm -> xnT bf16
    groupnorm_t_kernel<<<B * NUM_GROUPS, 256, 0, stream>>>(x, gn_gamma, gn_beta, xnT);

    // 2. Weights -> bf16
    wconv_kernel<<<1024, 256, 0, stream>>>(qkv_w, proj_w, wqb);

    // 3. QKV MFMA GEMM (writes Qt, Kt, Vb directly)
    {
        dim3 grid(HW / 128, (3 * C) / 128, B);
        qkv_mfma_kernel<<<grid, 256, 0, stream>>>(wqb, xnT, qkv_b, Qt, Kt, Vb);
    }

    // 4. MFMA flash attention -> attnT bf16 (256 queries per block)
    {
        dim3 grid(B * NUM_HEADS, HW / 256);
        attn_mfma_kernel<<<grid, 256, 0, stream>>>(Qt, Kt, Vb, attnT);
    }

    // 5. Proj MFMA GEMM + bias + residual -> fp32 out
    {
        dim3 grid(HW / 128, C / 128, B);
        proj_mfma_kernel<<<grid, 256, 0, stream>>>(wpb, attnT, proj_b, x, out);
    }
}